// Round 3
// baseline (1003.826 us; speedup 1.0000x reference)
//
#include <hip/hip_runtime.h>

// Sinkhorn (L1 cost), n=2048, d=64, eps=100, 10 frozen-on-converge iters.
// Multi-kernel, XCD-pinned: rows [256g, 256g+256) live on XCD g's L2 in every
// kernel (block b -> XCD b%8 round-robin). Convergence chain via last-block.

#define N 2048
#define EPS 100.0f
#define INV_EPS 0.01f
#define LOG_MU (-7.6246189861593985f)   // log(1/2048)
#define NITER 10
#define TOL 0.1f

__device__ __forceinline__ float wave_sum(float s) {
  #pragma unroll
  for (int off = 32; off > 0; off >>= 1) s += __shfl_down(s, off, 64);
  return s;
}

// ---------------- init: hist slot 0 = zeros, state scalars, counters ----------------
__global__ __launch_bounds__(256) void init_kernel(float* __restrict__ u0, float* __restrict__ v0,
                                                   int* __restrict__ idx_arr, int* __restrict__ done_arr,
                                                   int* __restrict__ ctrs) {
  int t = blockIdx.x * 256 + threadIdx.x;
  if (t < N) { u0[t] = 0.f; v0[t] = 0.f; }
  if (t <= NITER) { idx_arr[t] = 0; done_arr[t] = 0; ctrs[t] = 0; }
}

// ---------------- C build: C[i][j] = sum_k |A[i][k]-B[j][k]|, XCD-mapped ----------------
// 1024 blocks: b%8 = XCD g -> i-row-group g (rows 256g..256g+255). 16x16 thr, 4x4 reg tile.
__global__ __launch_bounds__(256) void build_c(const float* __restrict__ A,
                                               const float* __restrict__ B,
                                               float* __restrict__ C) {
  __shared__ float As[64][68];   // transposed [k][i], stride 68 (16B-aligned rows)
  __shared__ float Bs[64][68];
  const int b = blockIdx.x;
  const int g = b & 7, t = b >> 3;          // t 0..127
  const int itl = t >> 5, jt = t & 31;      // itl 0..3
  const int i0 = (g * 4 + itl) * 64, j0 = jt * 64;
  const int tid = threadIdx.x;
  #pragma unroll
  for (int e = 0; e < 16; ++e) {
    int idx = e * 256 + tid;
    int r = idx >> 6, k = idx & 63;         // coalesced global reads along k
    As[k][r] = A[(i0 + r) * 64 + k];
    Bs[k][r] = B[(j0 + r) * 64 + k];
  }
  __syncthreads();
  const int ty = tid >> 4, tx = tid & 15;   // 16x16, 4 rows x 4 cols each
  float acc[4][4] = {};
  #pragma unroll 8
  for (int k = 0; k < 64; ++k) {
    float4 av = *(const float4*)&As[k][ty * 4];
    float4 bv = *(const float4*)&Bs[k][tx * 4];
    float a[4] = {av.x, av.y, av.z, av.w};
    float c[4] = {bv.x, bv.y, bv.z, bv.w};
    #pragma unroll
    for (int p = 0; p < 4; ++p)
      #pragma unroll
      for (int q = 0; q < 4; ++q)
        acc[p][q] += fabsf(a[p] - c[q]);
  }
  #pragma unroll
  for (int p = 0; p < 4; ++p) {
    float4 o = make_float4(acc[p][0], acc[p][1], acc[p][2], acc[p][3]);
    *(float4*)&C[(size_t)(i0 + ty * 4 + p) * N + j0 + tx * 4] = o;
  }
}

// ---------------- row pass: u_new[r] = eps*(log_mu - log(rowsum+1e-6)) + u_comm[r] ----------------
// 2048 blocks: r = (b%8)*256 + b/8  (XCD-local C row)
__global__ __launch_bounds__(256) void row_pass(const float* __restrict__ C,
    const float* __restrict__ u_hist, const float* __restrict__ v_hist,
    float* __restrict__ u_out, const int* __restrict__ idx_arr, int it) {
  const int b = blockIdx.x;
  const int r = ((b & 7) << 8) + (b >> 3);
  const int idx = idx_arr[it];
  const float* __restrict__ vs = v_hist + (size_t)idx * N;
  const float ui = u_hist[(size_t)idx * N + r];
  const float* __restrict__ Crow = C + (size_t)r * N;
  const int j0 = threadIdx.x * 8;
  float4 c0 = *(const float4*)(Crow + j0);
  float4 c1 = *(const float4*)(Crow + j0 + 4);
  float4 v0 = *(const float4*)(vs + j0);
  float4 v1 = *(const float4*)(vs + j0 + 4);
  float s = expf((ui + v0.x - c0.x) * INV_EPS) + expf((ui + v0.y - c0.y) * INV_EPS)
          + expf((ui + v0.z - c0.z) * INV_EPS) + expf((ui + v0.w - c0.w) * INV_EPS)
          + expf((ui + v1.x - c1.x) * INV_EPS) + expf((ui + v1.y - c1.y) * INV_EPS)
          + expf((ui + v1.z - c1.z) * INV_EPS) + expf((ui + v1.w - c1.w) * INV_EPS);
  s = wave_sum(s);
  __shared__ float sh[4];
  if ((threadIdx.x & 63) == 0) sh[threadIdx.x >> 6] = s;
  __syncthreads();
  if (threadIdx.x == 0) {
    float rs = (sh[0] + sh[1]) + (sh[2] + sh[3]);
    u_out[r] = EPS * (LOG_MU - logf(rs + 1e-6f)) + ui;
  }
}

// ---------------- col pass + last-block finish ----------------
// 512 blocks: g=b%8, s=b/8; rt = g*2 + s/32 (rows rt*128..+128, on XCD g), jt = s%32.
__global__ __launch_bounds__(512) void col_pass(const float* __restrict__ C,
    const float* __restrict__ u_hist, const float* __restrict__ v_hist,
    float* __restrict__ part, float* __restrict__ v_out,
    int* __restrict__ idx_arr, int* __restrict__ done_arr,
    float* __restrict__ err_out, int* __restrict__ ctr, int it) {
  const int b = blockIdx.x;
  const int g = b & 7, s_ = b >> 3;
  const int rt = g * 2 + (s_ >> 5);
  const int jt = s_ & 31;
  const int tid = threadIdx.x, w = tid >> 6, lane = tid & 63;
  const int idx = idx_arr[it];
  const float* __restrict__ unew = u_hist + (size_t)(it + 1) * N;
  const int j = jt * 64 + lane;
  const float vj = v_hist[(size_t)idx * N + j];
  float acc = 0.f;
  const int ib = rt * 128;
  #pragma unroll 4
  for (int m = 0; m < 16; ++m) {
    int i = ib + w + m * 8;   // wave reads 64 consecutive floats of row i (256B)
    acc += expf((unew[i] + vj - C[(size_t)i * N + j]) * INV_EPS);
  }
  __shared__ float sh[8][64];
  sh[w][lane] = acc;
  __syncthreads();
  if (tid < 64) {
    float tt = ((sh[0][tid] + sh[1][tid]) + (sh[2][tid] + sh[3][tid]))
             + ((sh[4][tid] + sh[5][tid]) + (sh[6][tid] + sh[7][tid]));
    part[rt * N + jt * 64 + tid] = tt;
  }
  // ---- last-block: reduce partials -> v_new, err, done/idx chain ----
  __threadfence();
  __syncthreads();
  __shared__ int lastBlk;
  if (tid == 0)
    lastBlk = (__hip_atomic_fetch_add(ctr, 1, __ATOMIC_ACQ_REL, __HIP_MEMORY_SCOPE_AGENT) == 511);
  __syncthreads();
  if (!lastBlk) return;
  __threadfence();
  const float* __restrict__ ucomm = u_hist + (size_t)idx * N;
  const float* __restrict__ vcomm = v_hist + (size_t)idx * N;
  float errloc = 0.f;
  #pragma unroll
  for (int q = 0; q < 4; ++q) {
    int jj = tid * 4 + q;
    float ssum = 0.f;
    #pragma unroll
    for (int rr = 0; rr < 16; ++rr) ssum += part[rr * N + jj];
    v_out[jj] = EPS * (LOG_MU - logf(ssum + 1e-6f)) + vcomm[jj];
    errloc += fabsf(unew[jj] - ucomm[jj]);   // jj doubles as row index 0..2047
  }
  errloc = wave_sum(errloc);
  __shared__ float she[8];
  if (lane == 0) she[w] = errloc;
  __syncthreads();
  if (tid == 0) {
    float errv = ((she[0] + she[1]) + (she[2] + she[3]))
               + ((she[4] + she[5]) + (she[6] + she[7]));
    int dprev = done_arr[it];
    err_out[it] = errv;
    done_arr[it + 1] = dprev | (errv < TOL ? 1 : 0);
    idx_arr[it + 1] = dprev ? idx : (it + 1);
  }
}

// ---------------- loss: sum exp((u+v-C)/eps)*C, + last-block final reduce ----------------
__global__ __launch_bounds__(256) void loss_pass(const float* __restrict__ C,
    const float* __restrict__ u_hist, const float* __restrict__ v_hist,
    float* __restrict__ losspart, const int* __restrict__ idx_arr,
    int* __restrict__ ctr, float* __restrict__ out) {
  const int b = blockIdx.x;
  const int r = ((b & 7) << 8) + (b >> 3);
  const int idx = idx_arr[NITER];
  const float* __restrict__ vs = v_hist + (size_t)idx * N;
  const float ui = u_hist[(size_t)idx * N + r];
  const float* __restrict__ Crow = C + (size_t)r * N;
  const int j0 = threadIdx.x * 8;
  float4 c0 = *(const float4*)(Crow + j0);
  float4 c1 = *(const float4*)(Crow + j0 + 4);
  float4 v0 = *(const float4*)(vs + j0);
  float4 v1 = *(const float4*)(vs + j0 + 4);
  float s = expf((ui + v0.x - c0.x) * INV_EPS) * c0.x + expf((ui + v0.y - c0.y) * INV_EPS) * c0.y
          + expf((ui + v0.z - c0.z) * INV_EPS) * c0.z + expf((ui + v0.w - c0.w) * INV_EPS) * c0.w
          + expf((ui + v1.x - c1.x) * INV_EPS) * c1.x + expf((ui + v1.y - c1.y) * INV_EPS) * c1.y
          + expf((ui + v1.z - c1.z) * INV_EPS) * c1.z + expf((ui + v1.w - c1.w) * INV_EPS) * c1.w;
  s = wave_sum(s);
  __shared__ float sh[4];
  if ((threadIdx.x & 63) == 0) sh[threadIdx.x >> 6] = s;
  __syncthreads();
  if (threadIdx.x == 0) losspart[r] = (sh[0] + sh[1]) + (sh[2] + sh[3]);
  __threadfence();
  __syncthreads();
  __shared__ int lastBlk;
  if (threadIdx.x == 0)
    lastBlk = (__hip_atomic_fetch_add(ctr, 1, __ATOMIC_ACQ_REL, __HIP_MEMORY_SCOPE_AGENT) == 2047);
  __syncthreads();
  if (!lastBlk) return;
  __threadfence();
  float a = 0.f;
  #pragma unroll
  for (int q = 0; q < 8; ++q) a += losspart[threadIdx.x * 8 + q];
  a = wave_sum(a);
  if ((threadIdx.x & 63) == 0) sh[threadIdx.x >> 6] = a;
  __syncthreads();
  if (threadIdx.x == 0) out[0] = (sh[0] + sh[1]) + (sh[2] + sh[3]);
}

extern "C" void kernel_launch(void* const* d_in, const int* in_sizes, int n_in,
                              void* d_out, int out_size, void* d_ws, size_t ws_size,
                              hipStream_t stream) {
  const float* A = (const float*)d_in[0];
  const float* B = (const float*)d_in[1];
  float* out = (float*)d_out;

  char* base = (char*)d_ws;
  float* C        = (float*)base;                               // 16 MiB
  float* u_hist   = (float*)(base + (size_t)N * N * 4);         // [11][N]
  float* v_hist   = u_hist + (size_t)(NITER + 1) * N;           // [11][N]
  float* part     = v_hist + (size_t)(NITER + 1) * N;           // [16][N]
  float* losspart = part + 16 * N;                              // [N]
  float* err_tot  = losspart + N;                               // [NITER]
  int*   idx_arr  = (int*)(err_tot + NITER);                    // [NITER+1]
  int*   done_arr = idx_arr + (NITER + 1);                      // [NITER+1]
  int*   ctrs     = done_arr + (NITER + 1);                     // [NITER+1]

  init_kernel<<<8, 256, 0, stream>>>(u_hist, v_hist, idx_arr, done_arr, ctrs);
  build_c<<<1024, 256, 0, stream>>>(A, B, C);
  for (int it = 0; it < NITER; ++it) {
    row_pass<<<2048, 256, 0, stream>>>(C, u_hist, v_hist,
                                       u_hist + (size_t)(it + 1) * N, idx_arr, it);
    col_pass<<<512, 512, 0, stream>>>(C, u_hist, v_hist, part,
                                      v_hist + (size_t)(it + 1) * N,
                                      idx_arr, done_arr, err_tot, ctrs + it, it);
  }
  loss_pass<<<2048, 256, 0, stream>>>(C, u_hist, v_hist, losspart, idx_arr,
                                      ctrs + NITER, out);
}

// Round 4
// 136.965 us; speedup vs baseline: 7.3291x; 7.3291x over previous
//
#include <hip/hip_runtime.h>

// Sinkhorn (L1 cost), n=2048, d=64, eps=100, 10 frozen-on-converge iters.
// Multi-kernel, XCD row-pinned, NO atomics / NO fences (round-3 lesson:
// same-address device-scope atomics serialize at ~100ns -> 196us tails).
// Convergence chain: history slots + idx/done arrays, written by block 0 of
// a tiny finish kernel; kernel boundaries provide cross-XCD visibility.

#define N 2048
#define EPS 100.0f
#define INV_EPS 0.01f
#define LOG_MU (-7.6246189861593985f)   // log(1/2048)
#define NITER 10
#define TOL 0.1f

__device__ __forceinline__ float wave_sum(float s) {
  #pragma unroll
  for (int off = 32; off > 0; off >>= 1) s += __shfl_down(s, off, 64);
  return s;
}

// deterministic block reduction (fixed tree order), result broadcast to all threads
__device__ __forceinline__ float block_sum_256(float s, float* sh4) {
  s = wave_sum(s);
  if ((threadIdx.x & 63) == 0) sh4[threadIdx.x >> 6] = s;
  __syncthreads();
  float r = (sh4[0] + sh4[1]) + (sh4[2] + sh4[3]);
  __syncthreads();
  return r;
}

// ---------------- init ----------------
__global__ __launch_bounds__(256) void init_kernel(float* __restrict__ u0,
                                                   float* __restrict__ v0,
                                                   int* __restrict__ idx_arr,
                                                   int* __restrict__ done_arr) {
  int t = blockIdx.x * 256 + threadIdx.x;
  if (t < N) { u0[t] = 0.f; v0[t] = 0.f; }
  if (t == 0) { idx_arr[0] = 0; done_arr[0] = 0; }
}

// ---------------- C build: C[i][j] = sum_k |A[i][k]-B[j][k]|, XCD-row-pinned ----------------
// 1024 blocks: g=b&7 -> rows [g*256, g*256+256). 16x16 threads, 4x4 register tile.
__global__ __launch_bounds__(256) void build_c(const float* __restrict__ A,
                                               const float* __restrict__ B,
                                               float* __restrict__ C) {
  __shared__ float As[64][68];   // transposed [k][i], stride 68
  __shared__ float Bs[64][68];
  const int b = blockIdx.x;
  const int g = b & 7, t = b >> 3;
  const int itl = t >> 5, jt = t & 31;
  const int i0 = (g * 4 + itl) * 64, j0 = jt * 64;
  const int tid = threadIdx.x;
  #pragma unroll
  for (int e = 0; e < 16; ++e) {
    int idx = e * 256 + tid;
    int r = idx >> 6, k = idx & 63;
    As[k][r] = A[(i0 + r) * 64 + k];
    Bs[k][r] = B[(j0 + r) * 64 + k];
  }
  __syncthreads();
  const int ty = tid >> 4, tx = tid & 15;
  float acc[4][4] = {};
  #pragma unroll 8
  for (int k = 0; k < 64; ++k) {
    float4 av = *(const float4*)&As[k][ty * 4];
    float4 bv = *(const float4*)&Bs[k][tx * 4];
    float a[4] = {av.x, av.y, av.z, av.w};
    float c[4] = {bv.x, bv.y, bv.z, bv.w};
    #pragma unroll
    for (int p = 0; p < 4; ++p)
      #pragma unroll
      for (int q = 0; q < 4; ++q)
        acc[p][q] += fabsf(a[p] - c[q]);
  }
  #pragma unroll
  for (int p = 0; p < 4; ++p) {
    float4 o = make_float4(acc[p][0], acc[p][1], acc[p][2], acc[p][3]);
    *(float4*)&C[(size_t)(i0 + ty * 4 + p) * N + j0 + tx * 4] = o;
  }
}

// ---------------- row pass: u_new[r] = eps*(log_mu - log(rowsum+1e-6)) + u_comm[r] ----------------
// 2048 blocks, r = (b&7)*256 + b/8 (XCD-local C row)
__global__ __launch_bounds__(256) void row_u_pass(const float* __restrict__ C,
    const float* __restrict__ u_hist, const float* __restrict__ v_hist,
    float* __restrict__ u_out, const int* __restrict__ idx_arr, int it) {
  const int r = ((blockIdx.x & 7) << 8) + (blockIdx.x >> 3);
  const int idx = idx_arr[it];
  const float* __restrict__ vs = v_hist + (size_t)idx * N;
  const float ui = u_hist[(size_t)idx * N + r];
  const float* __restrict__ Crow = C + (size_t)r * N;
  float s = 0.f;
  #pragma unroll
  for (int p = 0; p < 2; ++p) {
    int j = (threadIdx.x << 2) + p * 1024;     // contiguous 1KB per wave-instr
    float4 c4 = *(const float4*)(Crow + j);
    float4 v4 = *(const float4*)(vs + j);
    s += expf((ui + v4.x - c4.x) * INV_EPS) + expf((ui + v4.y - c4.y) * INV_EPS)
       + expf((ui + v4.z - c4.z) * INV_EPS) + expf((ui + v4.w - c4.w) * INV_EPS);
  }
  __shared__ float sh4[4];
  s = block_sum_256(s, sh4);
  if (threadIdx.x == 0) u_out[r] = EPS * (LOG_MU - logf(s + 1e-6f)) + ui;
}

// ---------------- col partials: part[rt][j] = sum over 128 rows of exp(M) ----------------
// 512 blocks x 512 thr: g=b&7, rt=g*2+(b>>3)/32 (rows XCD-local), jt=(b>>3)%32
__global__ __launch_bounds__(512) void col_part(const float* __restrict__ C,
    const float* __restrict__ u_hist, const float* __restrict__ v_hist,
    float* __restrict__ part, const int* __restrict__ idx_arr, int it) {
  const int b = blockIdx.x;
  const int g = b & 7, s_ = b >> 3;
  const int rt = g * 2 + (s_ >> 5);
  const int jt = s_ & 31;
  const int tid = threadIdx.x, w = tid >> 6, lane = tid & 63;
  const int idx = idx_arr[it];
  const float* __restrict__ unew = u_hist + (size_t)(it + 1) * N;
  const int j = jt * 64 + lane;
  const float vj = v_hist[(size_t)idx * N + j];
  float acc = 0.f;
  const int ib = rt * 128;
  #pragma unroll 4
  for (int m = 0; m < 16; ++m) {
    int i = ib + w + m * 8;    // wave reads 64 consecutive floats of row i (256B)
    acc += expf((unew[i] + vj - C[(size_t)i * N + j]) * INV_EPS);
  }
  __shared__ float sh[8][64];
  sh[w][lane] = acc;
  __syncthreads();
  if (tid < 64) {
    float tt = ((sh[0][tid] + sh[1][tid]) + (sh[2][tid] + sh[3][tid]))
             + ((sh[4][tid] + sh[5][tid]) + (sh[6][tid] + sh[7][tid]));
    part[rt * N + jt * 64 + tid] = tt;
  }
}

// ---------------- col finish: v_new + (block 0) err / done / idx chain ----------------
// 8 blocks x 256 thr; block b owns j in [b*256, b*256+256)
__global__ __launch_bounds__(256) void col_fin(const float* __restrict__ part,
    const float* __restrict__ u_hist, const float* __restrict__ v_hist,
    float* __restrict__ v_out, int* __restrict__ idx_arr,
    int* __restrict__ done_arr, int it) {
  const int idx = idx_arr[it];
  const int j = blockIdx.x * 256 + threadIdx.x;
  float ssum = 0.f;
  #pragma unroll
  for (int rr = 0; rr < 16; ++rr) ssum += part[rr * N + j];
  const float vj = v_hist[(size_t)idx * N + j];
  v_out[j] = EPS * (LOG_MU - logf(ssum + 1e-6f)) + vj;
  if (blockIdx.x == 0) {   // block-uniform branch: err + convergence chain
    const float* __restrict__ unew  = u_hist + (size_t)(it + 1) * N;
    const float* __restrict__ ucomm = u_hist + (size_t)idx * N;
    float e = 0.f;
    #pragma unroll
    for (int p = 0; p < 2; ++p) {
      int i = (threadIdx.x << 2) + p * 1024;
      float4 un = *(const float4*)(unew + i);
      float4 uc = *(const float4*)(ucomm + i);
      e += fabsf(un.x - uc.x) + fabsf(un.y - uc.y)
         + fabsf(un.z - uc.z) + fabsf(un.w - uc.w);
    }
    __shared__ float sh4[4];
    e = block_sum_256(e, sh4);
    if (threadIdx.x == 0) {
      int dprev = done_arr[it];
      idx_arr[it + 1] = dprev ? idx : (it + 1);
      done_arr[it + 1] = dprev | (e < TOL ? 1 : 0);
    }
  }
}

// ---------------- loss: rowpart[r] = sum_j exp(M[r][j]) * C[r][j] ----------------
__global__ __launch_bounds__(256) void loss_pass(const float* __restrict__ C,
    const float* __restrict__ u_hist, const float* __restrict__ v_hist,
    float* __restrict__ rowpart, const int* __restrict__ idx_arr) {
  const int r = ((blockIdx.x & 7) << 8) + (blockIdx.x >> 3);
  const int idx = idx_arr[NITER];
  const float* __restrict__ vs = v_hist + (size_t)idx * N;
  const float ui = u_hist[(size_t)idx * N + r];
  const float* __restrict__ Crow = C + (size_t)r * N;
  float s = 0.f;
  #pragma unroll
  for (int p = 0; p < 2; ++p) {
    int j = (threadIdx.x << 2) + p * 1024;
    float4 c4 = *(const float4*)(Crow + j);
    float4 v4 = *(const float4*)(vs + j);
    s += expf((ui + v4.x - c4.x) * INV_EPS) * c4.x
       + expf((ui + v4.y - c4.y) * INV_EPS) * c4.y
       + expf((ui + v4.z - c4.z) * INV_EPS) * c4.z
       + expf((ui + v4.w - c4.w) * INV_EPS) * c4.w;
  }
  __shared__ float sh4[4];
  s = block_sum_256(s, sh4);
  if (threadIdx.x == 0) rowpart[r] = s;
}

__global__ __launch_bounds__(256) void loss_reduce(const float* __restrict__ rowpart,
                                                   float* __restrict__ out) {
  float s = 0.f;
  #pragma unroll
  for (int p = 0; p < 2; ++p) {
    int i = (threadIdx.x << 2) + p * 1024;
    float4 r4 = *(const float4*)(rowpart + i);
    s += (r4.x + r4.y) + (r4.z + r4.w);
  }
  __shared__ float sh4[4];
  s = block_sum_256(s, sh4);
  if (threadIdx.x == 0) out[0] = s;
}

extern "C" void kernel_launch(void* const* d_in, const int* in_sizes, int n_in,
                              void* d_out, int out_size, void* d_ws, size_t ws_size,
                              hipStream_t stream) {
  const float* A = (const float*)d_in[0];
  const float* B = (const float*)d_in[1];
  float* out = (float*)d_out;

  char* base = (char*)d_ws;
  float* C        = (float*)base;                               // 16 MiB
  float* u_hist   = (float*)(base + (size_t)N * N * 4);         // [11][N]
  float* v_hist   = u_hist + (size_t)(NITER + 1) * N;           // [11][N]
  float* part     = v_hist + (size_t)(NITER + 1) * N;           // [16][N]
  float* rowpart  = part + 16 * N;                              // [N]
  int*   idx_arr  = (int*)(rowpart + N);                        // [NITER+1]
  int*   done_arr = idx_arr + (NITER + 1);                      // [NITER+1]

  init_kernel<<<8, 256, 0, stream>>>(u_hist, v_hist, idx_arr, done_arr);
  build_c<<<1024, 256, 0, stream>>>(A, B, C);
  for (int it = 0; it < NITER; ++it) {
    row_u_pass<<<2048, 256, 0, stream>>>(C, u_hist, v_hist,
                                         u_hist + (size_t)(it + 1) * N, idx_arr, it);
    col_part<<<512, 512, 0, stream>>>(C, u_hist, v_hist, part, idx_arr, it);
    col_fin<<<8, 256, 0, stream>>>(part, u_hist, v_hist,
                                   v_hist + (size_t)(it + 1) * N,
                                   idx_arr, done_arr, it);
  }
  loss_pass<<<2048, 256, 0, stream>>>(C, u_hist, v_hist, rowpart, idx_arr);
  loss_reduce<<<1, 256, 0, stream>>>(rowpart, out);
}